// Round 5
// baseline (1989.892 us; speedup 1.0000x reference)
//
#include <hip/hip_runtime.h>
#include <hip/hip_bf16.h>

// Fused LN -> QKV projection (bf16 MFMA, 256x256 tile, BK=32, 64KB LDS,
// 2 blocks/CU for TLP latency hiding) with RoPE fused into the GEMM epilogue.
// x:(2,4096,2048) f32; wq/wk/wv:(2048,2048) f32 row-major [e][d]; out: q,k,v
// each (2,16,4096,128) f32 concatenated.

typedef float f32x4 __attribute__((ext_vector_type(4)));
typedef __bf16 bf16x8 __attribute__((ext_vector_type(8)));
typedef __bf16 bf16x4 __attribute__((ext_vector_type(4)));

#define DM    2048
#define NSEQ  4096
#define NH    16
#define HD    128
#define NROWS 8192
#define MAT_ELEMS (2ull*NH*NSEQ*HD)

// ---------- async global->LDS (16B/lane, wave-uniform LDS base) --------------
typedef __attribute__((address_space(1))) const void GV;
typedef __attribute__((address_space(3))) void LV;
__device__ __forceinline__ void gload_lds16(const void* g, void* l) {
    __builtin_amdgcn_global_load_lds((GV*)g, (LV*)l, 16, 0, 0);
}

// ---------------------- LayerNorm + bf16 cast --------------------------------
__global__ __launch_bounds__(256)
void ln_kernel(const float* __restrict__ x, const float* __restrict__ g,
               const float* __restrict__ be, __bf16* __restrict__ xnb) {
    int row = blockIdx.x;
    int tid = threadIdx.x;
    const float4* xr = (const float4*)(x + (size_t)row * DM);
    float4 v0 = xr[tid];
    float4 v1 = xr[tid + 256];
    float s  = v0.x + v0.y + v0.z + v0.w + v1.x + v1.y + v1.z + v1.w;
    float ss = v0.x*v0.x + v0.y*v0.y + v0.z*v0.z + v0.w*v0.w
             + v1.x*v1.x + v1.y*v1.y + v1.z*v1.z + v1.w*v1.w;
#pragma unroll
    for (int o = 32; o > 0; o >>= 1) {
        s  += __shfl_down(s, o);
        ss += __shfl_down(ss, o);
    }
    __shared__ float red[10];
    int wave = tid >> 6, lane = tid & 63;
    if (lane == 0) { red[wave] = s; red[4 + wave] = ss; }
    __syncthreads();
    if (tid == 0) {
        float S  = red[0] + red[1] + red[2] + red[3];
        float SS = red[4] + red[5] + red[6] + red[7];
        float mu  = S * (1.0f / DM);
        float var = SS * (1.0f / DM) - mu * mu;
        red[8] = mu;
        red[9] = rsqrtf(var + 1e-5f);
    }
    __syncthreads();
    float mu = red[8], rs = red[9];

    const float4* gp = (const float4*)g;
    const float4* bp = (const float4*)be;
    bf16x4* orow = (bf16x4*)(xnb + (size_t)row * DM);
    {
        float4 g0 = gp[tid], b0 = bp[tid];
        bf16x4 o;
        o[0] = (__bf16)((v0.x - mu) * rs * g0.x + b0.x);
        o[1] = (__bf16)((v0.y - mu) * rs * g0.y + b0.y);
        o[2] = (__bf16)((v0.z - mu) * rs * g0.z + b0.z);
        o[3] = (__bf16)((v0.w - mu) * rs * g0.w + b0.w);
        orow[tid] = o;
    }
    {
        float4 g1 = gp[tid + 256], b1 = bp[tid + 256];
        bf16x4 o;
        o[0] = (__bf16)((v1.x - mu) * rs * g1.x + b1.x);
        o[1] = (__bf16)((v1.y - mu) * rs * g1.y + b1.y);
        o[2] = (__bf16)((v1.z - mu) * rs * g1.z + b1.z);
        o[3] = (__bf16)((v1.w - mu) * rs * g1.w + b1.w);
        orow[tid + 256] = o;
    }
}

// ---------------- f32 -> bf16 conversion, all 3 weights in one launch --------
__global__ __launch_bounds__(256)
void cvt3_kernel(const float* __restrict__ a0, const float* __restrict__ a1,
                 const float* __restrict__ a2, __bf16* __restrict__ o) {
    int bid = blockIdx.x;                       // 0..6143
    const float* a = (bid < 2048) ? a0 : (bid < 4096) ? a1 : a2;
    size_t base = ((size_t)(bid & 2047) * 256 + threadIdx.x) * 8;
    float4 v0 = *(const float4*)(a + base);
    float4 v1 = *(const float4*)(a + base + 4);
    bf16x8 r;
    r[0] = (__bf16)v0.x; r[1] = (__bf16)v0.y; r[2] = (__bf16)v0.z; r[3] = (__bf16)v0.w;
    r[4] = (__bf16)v1.x; r[5] = (__bf16)v1.y; r[6] = (__bf16)v1.z; r[7] = (__bf16)v1.w;
    *(bf16x8*)(o + (size_t)(bid >> 11) * 4194304 + base) = r;
}

// =====================  256x256 BK=32 QKV GEMM, 2 blocks/CU  =================
// C[r][e] = sum_d Xn[r][d] * W[e][d].  8 waves (2Mx4N), per-wave 128x64 out.
// LDS 64 KiB: As/Bs [2 bufs][256x32], each buf = 2 units of 8 KB:
//   A0 = A rows {0-63,128-191}, A1 = {64-127,192-255} (unit-row u, 32-elem
//   rows); B likewise.  Swizzle: 16B slot s of unit-row u stored at s^((u>>1)&3)
//   (2-way bank aliasing only = free).  Waits VM4/VM4 formally cover the NEXT
//   phase's reads (3-phase issue->use distance, barrier'd cross-wave).

__device__ __forceinline__ void loadA4(bf16x8 (&a)[4], const __bf16* Sp,
                                       int base, int o0) {
#pragma unroll
    for (int mi = 0; mi < 4; mi++)
        a[mi] = *(const bf16x8*)(Sp + base + mi * 512 + o0);
}
__device__ __forceinline__ void loadB4(bf16x8 (&b)[4], const __bf16* Sp,
                                       int base, int o0) {
#pragma unroll
    for (int ni = 0; ni < 4; ni++)
        b[ni] = *(const bf16x8*)(Sp + (ni >> 1) * 4096 + base + (ni & 1) * 512 + o0);
}

template<int RB>
__device__ __forceinline__ void cluster(f32x4 (&acc)[8][4], bf16x8 (&a)[4],
                                        bf16x8 (&b)[4]) {
    __builtin_amdgcn_s_setprio(1);
#pragma unroll
    for (int mi = 0; mi < 4; mi++)
#pragma unroll
        for (int ni = 0; ni < 4; ni++)
            acc[RB + mi][ni] = __builtin_amdgcn_mfma_f32_16x16x32_bf16(
                a[mi], b[ni], acc[RB + mi][ni], 0, 0, 0);
    __builtin_amdgcn_s_setprio(0);
}

#define FENCE asm volatile("" ::: "memory")
#define BAR   do { FENCE; __builtin_amdgcn_s_barrier(); FENCE; } while (0)
#define VM4   asm volatile("s_waitcnt vmcnt(4)" ::: "memory")
#define VM1   asm volatile("s_waitcnt vmcnt(1)" ::: "memory")
#define VM0   asm volatile("s_waitcnt vmcnt(0)" ::: "memory")
#define VMX   do {} while (0)

// stage unit macros: thread t covers unit-row u=t>>2, global 16B slot
// (t&3)^((u>>1)&3) (pre-swizzled source, linear LDS dest = t*16B in unit).
#define STGA1(Q, kt)    gload_lds16(pA1 + (kt) * 32, &As[Q][4096 + t8])
#define STGB01A0(P, kt) do { \
    gload_lds16(pB0 + (kt) * 32, &Bs[P][t8]); \
    gload_lds16(pB1 + (kt) * 32, &Bs[P][4096 + t8]); \
    gload_lds16(pA0 + (kt) * 32, &As[P][t8]); \
} while (0)

#define KSTEP(kt, P, Q, SA1, SB, WA, WB) do { \
    /* phA: acc rows 0-3; reads A0,B0,B1(kt) (covered by prev phB wait+BAR) */ \
    loadA4(a, &As[P][0], baseA, o0); \
    loadB4(b, &Bs[P][0], baseB, o0); \
    if (SA1) STGA1(Q, (kt) + 1); \
    WA; BAR; cluster<0>(acc, a, b); BAR; \
    /* phB: acc rows 4-7; reads A1(kt) (covered by phA wait+BAR) */ \
    loadA4(a, &As[P][4096], baseA, o0); \
    if (SB) STGB01A0(P, (kt) + 2); \
    WB; BAR; cluster<4>(acc, a, b); BAR; \
} while (0)

__global__ __launch_bounds__(512, 4)
void gemm_qkv(const __bf16* __restrict__ A,
              const __bf16* __restrict__ Wq,
              const __bf16* __restrict__ Wk,
              const __bf16* __restrict__ Wv,
              float* __restrict__ out) {
    __shared__ __bf16 As[2][8192];   // 2 bufs x 256x32 (unit pairs), 16 KB each
    __shared__ __bf16 Bs[2][8192];

    int tid = threadIdx.x;
    int w = tid >> 6, l = tid & 63;
    int wm = w >> 2, wn = w & 3;

    // T1: bijective XCD swizzle (768 % 8 == 0)
    int bid = blockIdx.x;
    int swz = (bid & 7) * 96 + (bid >> 3);
    int mt = swz & 31, nt = swz >> 5;          // mt:0..31  nt:0..23
    int mat = nt >> 3, ntb = nt & 7;
    const __bf16* Wp = (mat == 0) ? Wq : (mat == 1) ? Wk : Wv;
    int row0 = mt * 256, colp = ntb * 256;

    // staging source pointers: u = t>>2 (unit-row), slot' = (t&3)^((u>>1)&3)
    int u = tid >> 2;
    int sl = ((tid & 3) ^ ((tid >> 3) & 3)) * 8;   // elems
    int g0 = u + (u & 64);                          // unit 0 global row
    const __bf16* pA0 = A  + (size_t)(row0 + g0) * DM + sl;
    const __bf16* pA1 = A  + (size_t)(row0 + g0 + 64) * DM + sl;
    const __bf16* pB0 = Wp + (size_t)(colp + g0) * DM + sl;
    const __bf16* pB1 = Wp + (size_t)(colp + g0 + 64) * DM + sl;
    int t8 = tid * 8;                               // LDS dest elems (16B/thread)

    // ds_read lane constants (elements); read-side XOR matches write swizzle
    // (row bits 1-2 are (l>>1)&3 for every mi/ni/wm/wn offset - all are mult. of 16/32/64)
    int baseA = (wm * 64 + (l & 15)) * 32;
    int baseB = ((wn & 1) * 32 + (wn >> 1) * 64 + (l & 15)) * 32;
    int o0 = ((l >> 4) ^ ((l >> 1) & 3)) * 8;

    // prologue: [B0,B1,A0](0)->buf0, A1(0)->buf0, [B0,B1,A0](1)->buf1  (7 loads)
    STGB01A0(0, 0);
    STGA1(0, 0);
    STGB01A0(1, 1);

    f32x4 acc[8][4];
#pragma unroll
    for (int i = 0; i < 8; i++)
#pragma unroll
        for (int j = 0; j < 4; j++)
            acc[i][j] = (f32x4){0.f, 0.f, 0.f, 0.f};

    bf16x8 a[4], b[4];

    VM4;          // oldest 3 = B0,B1,A0(kt0) landed before first ds_read
    BAR;

#pragma unroll 1
    for (int kt = 0; kt < 62; kt += 2) {
        KSTEP(kt,     0, 1, 1, 1, VM4, VM4);
        KSTEP(kt + 1, 1, 0, 1, 1, VM4, VM4);
    }
    KSTEP(62, 0, 1, 1, 0, VM4, VM1);
    KSTEP(63, 1, 0, 0, 0, VM0, VMX);

    // ---------------- epilogue: head-split layout + fused RoPE ---------------
    // acc[mi][ni] col = (wn&1)*32 + (ni&1)*16 + (wn>>1)*128 + (ni>>1)*64 + (l&15)
    // -> (acc[mi][ni], acc[mi][ni+2]) is the (d, d+64) rotation pair, ni=0,1.
    float* op = out + (size_t)mat * MAT_ELEMS;
    int hd_lo = (wn & 1) * 32 + (l & 15);                 // d for ni=0 (0..63)
    int head = ntb * 2 + (wn >> 1);
    int r_base = row0 + wm * 128 + ((l >> 4) << 2);
    float if0 = exp2f(-0.20762051f * (float)hd_lo);        // 10000^(-d/64)
    float if1 = exp2f(-0.20762051f * (float)(hd_lo + 16));

    if (mat < 2) {
#pragma unroll
        for (int mi = 0; mi < 8; mi++) {
#pragma unroll
            for (int j = 0; j < 4; j++) {
                int r = r_base + mi * 16 + j;
                int b2 = r >> 12, n = r & 4095;
                float fn = (float)n;
                float* rowp = op + ((size_t)((b2 * NH + head) * NSEQ + n)) * HD;
#pragma unroll
                for (int ni = 0; ni < 2; ni++) {
                    float lo = acc[mi][ni][j], hi = acc[mi][ni + 2][j];
                    float s, c;
                    __sincosf(fn * (ni ? if1 : if0), &s, &c);
                    rowp[hd_lo + ni * 16]      = lo * c - hi * s;
                    rowp[hd_lo + ni * 16 + 64] = hi * c + lo * s;
                }
            }
        }
    } else {
#pragma unroll
        for (int mi = 0; mi < 8; mi++) {
#pragma unroll
            for (int j = 0; j < 4; j++) {
                int r = r_base + mi * 16 + j;
                int b2 = r >> 12, n = r & 4095;
                float* rowp = op + ((size_t)((b2 * NH + head) * NSEQ + n)) * HD;
#pragma unroll
                for (int ni = 0; ni < 2; ni++) {
                    rowp[hd_lo + ni * 16]      = acc[mi][ni][j];
                    rowp[hd_lo + ni * 16 + 64] = acc[mi][ni + 2][j];
                }
            }
        }
    }
}

// ---------------------------------------------------------------------------
extern "C" void kernel_launch(void* const* d_in, const int* in_sizes, int n_in,
                              void* d_out, int out_size, void* d_ws, size_t ws_size,
                              hipStream_t stream) {
    const float* x  = (const float*)d_in[0];
    const float* g  = (const float*)d_in[1];
    const float* be = (const float*)d_in[2];
    const float* wq = (const float*)d_in[3];
    const float* wk = (const float*)d_in[4];
    const float* wv = (const float*)d_in[5];
    float* out = (float*)d_out;

    char* ws = (char*)d_ws;
    __bf16* xnb = (__bf16*)ws;                                   // 32 MB
    __bf16* wb  = (__bf16*)(ws + 33554432);                      // 24 MB (q,k,v)

    ln_kernel<<<NROWS, 256, 0, stream>>>(x, g, be, xnb);
    cvt3_kernel<<<6144, 256, 0, stream>>>(wq, wk, wv, wb);
    gemm_qkv<<<768, 512, 0, stream>>>(xnb, wb, wb + 4194304, wb + 8388608, out);
}

// Round 6
// 225.271 us; speedup vs baseline: 8.8333x; 8.8333x over previous
//
#include <hip/hip_runtime.h>
#include <hip/hip_bf16.h>

// Fused LN -> QKV projection (bf16 MFMA, 256^2 deep-pipelined schedule) with
// RoPE fused into the GEMM epilogue.  R6: 2D-clustered XCD tile mapping
// (4mt x 8nt per XCD-round) for A+B L2 reuse; GEMM core reverted to R3.
// x:(2,4096,2048) f32; wq/wk/wv:(2048,2048) f32 row-major [e][d]; out: q,k,v
// each (2,16,4096,128) f32 concatenated.

typedef float f32x4 __attribute__((ext_vector_type(4)));
typedef __bf16 bf16x8 __attribute__((ext_vector_type(8)));
typedef __bf16 bf16x4 __attribute__((ext_vector_type(4)));

#define DM    2048
#define NSEQ  4096
#define NH    16
#define HD    128
#define NROWS 8192
#define MAT_ELEMS (2ull*NH*NSEQ*HD)

// ---------- async global->LDS (16B/lane, wave-uniform LDS base) --------------
typedef __attribute__((address_space(1))) const void GV;
typedef __attribute__((address_space(3))) void LV;
__device__ __forceinline__ void gload_lds16(const void* g, void* l) {
    __builtin_amdgcn_global_load_lds((GV*)g, (LV*)l, 16, 0, 0);
}

// ---------------------- LayerNorm + bf16 cast --------------------------------
__global__ __launch_bounds__(256)
void ln_kernel(const float* __restrict__ x, const float* __restrict__ g,
               const float* __restrict__ be, __bf16* __restrict__ xnb) {
    int row = blockIdx.x;
    int tid = threadIdx.x;
    const float4* xr = (const float4*)(x + (size_t)row * DM);
    float4 v0 = xr[tid];
    float4 v1 = xr[tid + 256];
    float s  = v0.x + v0.y + v0.z + v0.w + v1.x + v1.y + v1.z + v1.w;
    float ss = v0.x*v0.x + v0.y*v0.y + v0.z*v0.z + v0.w*v0.w
             + v1.x*v1.x + v1.y*v1.y + v1.z*v1.z + v1.w*v1.w;
#pragma unroll
    for (int o = 32; o > 0; o >>= 1) {
        s  += __shfl_down(s, o);
        ss += __shfl_down(ss, o);
    }
    __shared__ float red[10];
    int wave = tid >> 6, lane = tid & 63;
    if (lane == 0) { red[wave] = s; red[4 + wave] = ss; }
    __syncthreads();
    if (tid == 0) {
        float S  = red[0] + red[1] + red[2] + red[3];
        float SS = red[4] + red[5] + red[6] + red[7];
        float mu  = S * (1.0f / DM);
        float var = SS * (1.0f / DM) - mu * mu;
        red[8] = mu;
        red[9] = rsqrtf(var + 1e-5f);
    }
    __syncthreads();
    float mu = red[8], rs = red[9];

    const float4* gp = (const float4*)g;
    const float4* bp = (const float4*)be;
    bf16x4* orow = (bf16x4*)(xnb + (size_t)row * DM);
    {
        float4 g0 = gp[tid], b0 = bp[tid];
        bf16x4 o;
        o[0] = (__bf16)((v0.x - mu) * rs * g0.x + b0.x);
        o[1] = (__bf16)((v0.y - mu) * rs * g0.y + b0.y);
        o[2] = (__bf16)((v0.z - mu) * rs * g0.z + b0.z);
        o[3] = (__bf16)((v0.w - mu) * rs * g0.w + b0.w);
        orow[tid] = o;
    }
    {
        float4 g1 = gp[tid + 256], b1 = bp[tid + 256];
        bf16x4 o;
        o[0] = (__bf16)((v1.x - mu) * rs * g1.x + b1.x);
        o[1] = (__bf16)((v1.y - mu) * rs * g1.y + b1.y);
        o[2] = (__bf16)((v1.z - mu) * rs * g1.z + b1.z);
        o[3] = (__bf16)((v1.w - mu) * rs * g1.w + b1.w);
        orow[tid + 256] = o;
    }
}

// ---------------- f32 -> bf16 conversion, all 3 weights in one launch --------
__global__ __launch_bounds__(256)
void cvt3_kernel(const float* __restrict__ a0, const float* __restrict__ a1,
                 const float* __restrict__ a2, __bf16* __restrict__ o) {
    int bid = blockIdx.x;                       // 0..6143
    const float* a = (bid < 2048) ? a0 : (bid < 4096) ? a1 : a2;
    size_t base = ((size_t)(bid & 2047) * 256 + threadIdx.x) * 8;
    float4 v0 = *(const float4*)(a + base);
    float4 v1 = *(const float4*)(a + base + 4);
    bf16x8 r;
    r[0] = (__bf16)v0.x; r[1] = (__bf16)v0.y; r[2] = (__bf16)v0.z; r[3] = (__bf16)v0.w;
    r[4] = (__bf16)v1.x; r[5] = (__bf16)v1.y; r[6] = (__bf16)v1.z; r[7] = (__bf16)v1.w;
    *(bf16x8*)(o + (size_t)(bid >> 11) * 4194304 + base) = r;
}

// =====================  256x256 deep-pipelined QKV GEMM  =====================
// (R3 core, verified.)  Tile 256x256, BK=64, 8 waves (2Mx4N), LDS 128KiB
// double-buffered, XOR-swizzle, 2-K-tile prefetch distance, counted vmcnt(8).
// RoPE applied in epilogue for q/k.

__device__ __forceinline__ void loadA4(bf16x8 (&a)[4][2], const __bf16* Sp,
                                       int base, int mb, int o0) {
#pragma unroll
    for (int mi = 0; mi < 4; mi++)
#pragma unroll
        for (int ks = 0; ks < 2; ks++)
            a[mi][ks] = *(const bf16x8*)(Sp + base + (mb + mi) * 1024 + (o0 ^ (ks * 32)));
}
// fragments f=0,1 at B rows base + f*16 + (cb>>1)*64
__device__ __forceinline__ void loadB2(bf16x8 (&b)[2][2], const __bf16* Sp,
                                       int base, int cb, int o0) {
#pragma unroll
    for (int f = 0; f < 2; f++)
#pragma unroll
        for (int ks = 0; ks < 2; ks++)
            b[f][ks] = *(const bf16x8*)(Sp + base + (f * 16 + (cb >> 1) * 64) * 64 + (o0 ^ (ks * 32)));
}

template<int RB, int CB>
__device__ __forceinline__ void cluster(f32x4 (&acc)[8][4], bf16x8 (&a)[4][2],
                                        bf16x8 (&b)[2][2]) {
    __builtin_amdgcn_s_setprio(1);
#pragma unroll
    for (int mi = 0; mi < 4; mi++)
#pragma unroll
        for (int ni = 0; ni < 2; ni++)
#pragma unroll
            for (int ks = 0; ks < 2; ks++)
                acc[RB + mi][CB + ni] = __builtin_amdgcn_mfma_f32_16x16x32_bf16(
                    a[mi][ks], b[ni][ks], acc[RB + mi][CB + ni], 0, 0, 0);
    __builtin_amdgcn_s_setprio(0);
}

#define FENCE asm volatile("" ::: "memory")
#define BAR   do { FENCE; __builtin_amdgcn_s_barrier(); FENCE; } while (0)
#define VM8   asm volatile("s_waitcnt vmcnt(8)" ::: "memory")
#define VM4   asm volatile("s_waitcnt vmcnt(4)" ::: "memory")
#define VM2   asm volatile("s_waitcnt vmcnt(2)" ::: "memory")
#define VM0   asm volatile("s_waitcnt vmcnt(0)" ::: "memory")
#define VMX   do {} while (0)

// stage A/B half HF (0: rows {0-63,128-191}; 1: rows {64-127,192-255}) of
// K-tile kt into buf P.  Per-wave: rowgroups {HF*8+w, HF*8+16+w}.
#define STGA(P, kt, HF) do { \
    gload_lds16(pA + (size_t)((HF) * 64 + w * 8) * DM + (kt) * 64,       &As[P][((HF) * 8 + w) * 512]); \
    gload_lds16(pA + (size_t)((HF) * 64 + 128 + w * 8) * DM + (kt) * 64, &As[P][((HF) * 8 + 16 + w) * 512]); \
} while (0)
#define STGB(P, kt, HF) do { \
    gload_lds16(pB + (size_t)((HF) * 64 + w * 8) * DM + (kt) * 64,       &Bs[P][((HF) * 8 + w) * 512]); \
    gload_lds16(pB + (size_t)((HF) * 64 + 128 + w * 8) * DM + (kt) * 64, &Bs[P][((HF) * 8 + 16 + w) * 512]); \
} while (0)

#define KTILE(kt, P, Q, SG0, SG1, SG2, SG3, W0, W1, W2, W3) do { \
    /* ph0: quad (0,0) */ \
    loadA4(a,  &As[P][0], baseA, 0, o0); \
    loadB2(b0, &Bs[P][0], baseB, 0, o0); \
    if (SG0) STGA(Q, (kt) + 1, 1);               /* U1(kt+1) */ \
    W0; BAR; cluster<0, 0>(acc, a, b0); BAR; \
    /* ph1: quad (0,2) */ \
    loadB2(b1, &Bs[P][0], baseB, 2, o0); \
    if (SG1) STGA(P, (kt) + 2, 0);               /* U0(kt+2) */ \
    W1; BAR; cluster<0, 2>(acc, a, b1); BAR; \
    /* ph2: quad (4,2) */ \
    loadA4(a, &As[P][0], baseA, 4, o0); \
    if (SG2) STGB(P, (kt) + 2, 0);               /* U2(kt+2) */ \
    W2; BAR; cluster<4, 2>(acc, a, b1); BAR; \
    /* ph3: quad (4,0) */ \
    if (SG3) STGB(P, (kt) + 2, 1);               /* U3(kt+2) */ \
    W3; BAR; cluster<4, 0>(acc, a, b0); BAR; \
} while (0)

__global__ __launch_bounds__(512, 2)
void gemm_qkv(const __bf16* __restrict__ A,
              const __bf16* __restrict__ Wq,
              const __bf16* __restrict__ Wk,
              const __bf16* __restrict__ Wv,
              float* __restrict__ out) {
    __shared__ __bf16 As[2][16384];   // 2 x 256x64
    __shared__ __bf16 Bs[2][16384];

    int tid = threadIdx.x;
    int w = tid >> 6, l = tid & 63;
    int wm = w >> 2, wn = w & 3;

    // R6: 2D-clustered XCD mapping.  xcd = bid&7 owns an 8mt x 12nt region;
    // each round of 32 co-resident blocks covers a 4x8 (or 8x4) cluster ->
    // A-panels reused 8x and B-panels 4x within the XCD's L2.
    int bid = blockIdx.x;
    int x = bid & 7;
    int ridx = bid >> 3;               // 0..95
    int q = ridx >> 5;                 // round 0,1,2
    int s = ridx & 31;
    int mtp, ntp;
    if (q == 0)      { mtp = s >> 3;       ntp = s & 7; }
    else if (q == 1) { mtp = 4 + (s >> 3); ntp = s & 7; }
    else             { mtp = s & 7;        ntp = 8 + (s >> 3); }
    int mt = (x & 3) * 8 + mtp;        // 0..31
    int nt = (x >> 2) * 12 + ntp;      // 0..23
    int mat = nt >> 3, ntb = nt & 7;
    const __bf16* Wp = (mat == 0) ? Wq : (mat == 1) ? Wk : Wv;
    int row0 = mt * 256, colp = ntb * 256;

    // staging base pointers: lane covers row lr of each 8-row group, 16B at
    // pre-swizzled col ((l&7)^(l>>3))*16B  (rule 21: swizzle source, linear dest)
    int lr = l >> 3;
    int lco = ((l & 7) ^ lr) * 8;
    const __bf16* pA = A  + (size_t)(row0 + lr) * DM + lco;
    const __bf16* pB = Wp + (size_t)(colp + lr) * DM + lco;

    // ds_read lane constants (elements); read-side XOR matches write swizzle
    int baseA = (wm * 128 + (l & 15)) * 64;
    int baseB = ((wn & 1) * 32 + (wn >> 1) * 128 + (l & 15)) * 64;
    int o0 = ((l >> 4) * 8) ^ ((l & 7) * 8);

    // prologue: kt0 {U0,U1,U2,U3} -> buf0 ; kt1 {U0,U2,U3} -> buf1
    STGA(0, 0, 0); STGA(0, 0, 1); STGB(0, 0, 0); STGB(0, 0, 1);
    STGA(1, 1, 0); STGB(1, 1, 0); STGB(1, 1, 1);

    f32x4 acc[8][4];
#pragma unroll
    for (int i = 0; i < 8; i++)
#pragma unroll
        for (int j = 0; j < 4; j++)
            acc[i][j] = (f32x4){0.f, 0.f, 0.f, 0.f};

    bf16x8 a[4][2], b0[2][2], b1[2][2];

    VM8;            // kt0 U0,U2 landed (8 newer instrs may be in flight)
    BAR;

#pragma unroll 1
    for (int kt = 0; kt < 30; kt += 2) {
        KTILE(kt,     0, 1, 1, 1, 1, 1, VM8, VM8, VMX, VM8);
        KTILE(kt + 1, 1, 0, 1, 1, 1, 1, VM8, VM8, VMX, VM8);
    }
    KTILE(30, 0, 1, 1, 0, 0, 0, VM8, VM8, VMX, VM4);
    KTILE(31, 1, 0, 0, 0, 0, 0, VM2, VM0, VMX, VMX);

    // ---------------- epilogue: head-split layout + fused RoPE ---------------
    // acc[mi][ni] col = (wn&1)*32 + (ni&1)*16 + (wn>>1)*128 + (ni>>1)*64 + (l&15)
    // -> (acc[mi][ni], acc[mi][ni+2]) is the (d, d+64) rotation pair, ni=0,1.
    float* op = out + (size_t)mat * MAT_ELEMS;
    int hd_lo = (wn & 1) * 32 + (l & 15);                 // d for ni=0 (0..63)
    int head = ntb * 2 + (wn >> 1);
    int r_base = row0 + wm * 128 + ((l >> 4) << 2);
    float if0 = exp2f(-0.20762051f * (float)hd_lo);        // 10000^(-d/64)
    float if1 = exp2f(-0.20762051f * (float)(hd_lo + 16));

    if (mat < 2) {
#pragma unroll
        for (int mi = 0; mi < 8; mi++) {
#pragma unroll
            for (int j = 0; j < 4; j++) {
                int r = r_base + mi * 16 + j;
                int b = r >> 12, n = r & 4095;
                float fn = (float)n;
                float* rowp = op + ((size_t)((b * NH + head) * NSEQ + n)) * HD;
#pragma unroll
                for (int ni = 0; ni < 2; ni++) {
                    float lo = acc[mi][ni][j], hi = acc[mi][ni + 2][j];
                    float sv, cv;
                    __sincosf(fn * (ni ? if1 : if0), &sv, &cv);
                    rowp[hd_lo + ni * 16]      = lo * cv - hi * sv;
                    rowp[hd_lo + ni * 16 + 64] = hi * cv + lo * sv;
                }
            }
        }
    } else {
#pragma unroll
        for (int mi = 0; mi < 8; mi++) {
#pragma unroll
            for (int j = 0; j < 4; j++) {
                int r = r_base + mi * 16 + j;
                int b = r >> 12, n = r & 4095;
                float* rowp = op + ((size_t)((b * NH + head) * NSEQ + n)) * HD;
#pragma unroll
                for (int ni = 0; ni < 2; ni++) {
                    rowp[hd_lo + ni * 16]      = acc[mi][ni][j];
                    rowp[hd_lo + ni * 16 + 64] = acc[mi][ni + 2][j];
                }
            }
        }
    }
}

// ---------------------------------------------------------------------------
extern "C" void kernel_launch(void* const* d_in, const int* in_sizes, int n_in,
                              void* d_out, int out_size, void* d_ws, size_t ws_size,
                              hipStream_t stream) {
    const float* x  = (const float*)d_in[0];
    const float* g  = (const float*)d_in[1];
    const float* be = (const float*)d_in[2];
    const float* wq = (const float*)d_in[3];
    const float* wk = (const float*)d_in[4];
    const float* wv = (const float*)d_in[5];
    float* out = (float*)d_out;

    char* ws = (char*)d_ws;
    __bf16* xnb = (__bf16*)ws;                                   // 32 MB
    __bf16* wb  = (__bf16*)(ws + 33554432);                      // 24 MB (q,k,v)

    ln_kernel<<<NROWS, 256, 0, stream>>>(x, g, be, xnb);
    cvt3_kernel<<<6144, 256, 0, stream>>>(wq, wk, wv, wb);
    gemm_qkv<<<768, 512, 0, stream>>>(xnb, wb, wb + 4194304, wb + 8388608, out);
}